// Round 6
// baseline (864.575 us; speedup 1.0000x reference)
//
#include <hip/hip_runtime.h>
#include <hip/hip_bf16.h>
#include <math.h>

#define NB 16
#define NIN 2048
#define NOUT 512
#define TT 1000
#define L_SRM 31
#define CAP2 768

// ---------------- kernel 1: transpose W [512][2048] -> WT [2048][512] ----------
__global__ void k_transpose(const float* __restrict__ W, float* __restrict__ WT) {
    int idx = blockIdx.x * 256 + threadIdx.x;   // over 2048*512
    int i = idx >> 9;        // input channel
    int o = idx & 511;       // output channel
    WT[idx] = W[o * NIN + i];
}

// ---------------- kernel 2: ballot-transpose spike extract --------------------
// block 256 thr = 4 waves. Tile: 64 inputs x 64 timesteps. No atomics.
// out: bits[n][t][ic] (u64), bit b of word ic <=> input i = ic*64+b active at t.
__global__ __launch_bounds__(256) void k_extract(const float* __restrict__ s,
                                                 unsigned long long* __restrict__ bits) {
    __shared__ float tile[64][65];          // padded: column reads conflict-free
    int tc = blockIdx.x;                    // t-chunk (16)
    int ic = blockIdx.y;                    // i-chunk (32)
    int n  = blockIdx.z;                    // batch (16)
    int t0 = tc * 64, i0 = ic * 64;
    int tid = threadIdx.x;
    int r   = tid >> 2;                     // tile row (input)
    int cq  = tid & 3;                      // col quarter
    const float* rp = s + ((size_t)(n * NIN + i0 + r)) * TT + t0;
    #pragma unroll
    for (int q = 0; q < 4; ++q) {
        int col = cq * 16 + q * 4;
        float4 v = make_float4(0.f, 0.f, 0.f, 0.f);
        if (t0 + col + 3 < TT) v = *(const float4*)(rp + col);
        tile[r][col]     = v.x;
        tile[r][col + 1] = v.y;
        tile[r][col + 2] = v.z;
        tile[r][col + 3] = v.w;
    }
    __syncthreads();
    int lane = tid & 63;
    int w    = tid >> 6;
    #pragma unroll
    for (int k = 0; k < 16; ++k) {
        int tl = w * 16 + k;
        if (t0 + tl >= TT) break;
        float val = tile[lane][tl];
        unsigned long long m = __ballot(val != 0.0f);
        if (lane == 0)
            bits[((size_t)n * TT + t0 + tl) * 32 + ic] = m;
    }
}

// ---------------- kernel 3: sparse accumulate z[n][t][o] = sum_{active i} WT[i][o]
// 128 threads/block, each thread owns 4 outputs (float4 row loads).
// f64 accumulation (exact ~1e-13); nontemporal z stores keep WT in L2.
__global__ __launch_bounds__(128) void k_spmm(const unsigned long long* __restrict__ bits,
                                              const float* __restrict__ WT,
                                              double* __restrict__ z) {
    int nt  = blockIdx.x;       // 0 .. NB*TT-1
    int tid = threadIdx.x;      // 128
    __shared__ int sidx[CAP2];  // active rows as element offsets (idx*512)
    __shared__ int s_cnt;
    if (tid < 64) {             // wave 0 compacts 32 bitmask words -> offset list
        unsigned long long w = (tid < 32) ? bits[(size_t)nt * 32 + tid] : 0ULL;
        int pc  = __popcll(w);
        int pre = pc;
        #pragma unroll
        for (int d = 1; d < 32; d <<= 1) {
            int x = __shfl_up(pre, d, 64);
            if (tid >= d) pre += x;
        }
        pre -= pc;              // exclusive prefix
        if (tid == 31) s_cnt = pre + pc;
        int base = tid * 64;
        while (w) {
            int b = __builtin_ctzll(w);
            if (pre < CAP2) sidx[pre] = (base + b) << 9;    // * NOUT
            ++pre;
            w &= w - 1;
        }
    }
    __syncthreads();
    int c = s_cnt;
    if (c > CAP2) c = CAP2;
    const float* wp = WT + (tid << 2);      // this thread's 4-output column
    double a0 = 0., a1 = 0., a2 = 0., a3 = 0.;
    double b0 = 0., b1 = 0., b2 = 0., b3 = 0.;
    int j = 0;
    for (; j + 1 < c; j += 2) {
        float4 u = *(const float4*)(wp + sidx[j]);
        float4 v = *(const float4*)(wp + sidx[j + 1]);
        a0 += (double)u.x; a1 += (double)u.y; a2 += (double)u.z; a3 += (double)u.w;
        b0 += (double)v.x; b1 += (double)v.y; b2 += (double)v.z; b3 += (double)v.w;
    }
    if (j < c) {
        float4 u = *(const float4*)(wp + sidx[j]);
        a0 += (double)u.x; a1 += (double)u.y; a2 += (double)u.z; a3 += (double)u.w;
    }
    double* zp = &z[(size_t)nt * NOUT + (tid << 2)];
    __builtin_nontemporal_store(a0 + b0, zp);
    __builtin_nontemporal_store(a1 + b1, zp + 1);
    __builtin_nontemporal_store(a2 + b2, zp + 2);
    __builtin_nontemporal_store(a3 + b3, zp + 3);
}

// ---------------- kernel 4: temporal conv wpsp[n][t][o] = sum_j srm[j]*z[n][t-j][o]
// block: 128 threads (one 128-o chunk); t-chunk 32, halo 30 -> 62 rows.
// LDS = 62*128*8 = 63488 B (< 64 KB).
__global__ __launch_bounds__(128) void k_conv(const double* __restrict__ z,
                                              double* __restrict__ wpsp) {
    __shared__ float srm_s[32];
    __shared__ double zs[62 * 128];
    int tid = threadIdx.x;
    if (tid < L_SRM) {
        // match np: f64 alpha samples cast to f32 (SRM_KERNEL values)
        double t = (double)tid;
        srm_s[tid] = (float)((t / 4.0) * exp(1.0 - t / 4.0));   // * TS(=1)
    }
    int tb = blockIdx.x * 32;
    int oc = blockIdx.y * 128;
    int n  = blockIdx.z;
    const double* zp = z + ((size_t)n * TT) * NOUT + oc;
    for (int r = 0; r < 62; ++r) {
        int t = tb - 30 + r;
        zs[r * 128 + tid] = (t >= 0 && t < TT) ? zp[(size_t)t * NOUT + tid] : 0.0;
    }
    __syncthreads();
    for (int tl = 0; tl < 32; ++tl) {
        int t = tb + tl;
        if (t >= TT) break;
        double acc = 0.0;
        #pragma unroll
        for (int jj = 0; jj < L_SRM; ++jj)
            acc += (double)srm_s[jj] * zs[(tl + 30 - jj) * 128 + tid];
        wpsp[((size_t)n * TT + t) * NOUT + oc + tid] = acc;
    }
}

// ---------------- kernel 5: spike scan, byte-table refractory, 2 streams/wave -
// block: 64 threads (1 wave) handles TWO independent (n, 64-o-chunk) traces;
// the two dependence chains interleave so the ~120cy Tb LDS latency of one
// hides under the other's compute. Numerics per stream unchanged (f64 sums of
// f32 REF_KERNEL values via byte-indexed partial-sum table).
__global__ __launch_bounds__(64) void k_scan(const double* __restrict__ wpsp,
                                             float* __restrict__ out) {
    __shared__ float  refTab[64];                         // f32 REF_KERNEL values
    __shared__ double Tb[8][256];                         // byte partial sums, 16 KB
    __shared__ __align__(16) double xbuf[2][2][16 * 64];  // [stream][dbuf], 32 KB
    __shared__ float  obuf[2][64 * 17];                   // [stream][o][t] padded
    int lane = threadIdx.x;
    {
        double d = (double)lane;
        refTab[lane] = (lane == 0) ? 0.0f
                     : (float)(-20.0 * (d / 4.0) * exp(1.0 - d / 4.0));
    }
    __syncthreads();
    for (int e = lane; e < 2048; e += 64) {
        int k = e >> 8, m = e & 255;
        double s = 0.0;
        #pragma unroll
        for (int j = 0; j < 8; ++j) {
            int idx = 8 * k + j + 1;
            if (((m >> j) & 1) && idx <= 63) s += (double)refTab[idx];
        }
        Tb[k][m] = s;
    }

    int st0 = blockIdx.x * 2, st1 = st0 + 1;             // stream ids (0..127)
    int nA = st0 >> 3, oA = (st0 & 7) << 6;
    int nB = st1 >> 3, oB = (st1 & 7) << 6;
    const double* wpA = wpsp + ((size_t)nA * TT) * NOUT + oA;
    const double* wpB = wpsp + ((size_t)nB * TT) * NOUT + oB;
    float* opA = out + ((size_t)(nA * NOUT) + oA + lane) * TT;
    float* opB = out + ((size_t)(nB * NOUT) + oB + lane) * TT;

    // stage nrows rows (64 f64) into xbuf[sb][buf]; 2 rows per issue:
    // lanes 0-31 row r cols 0..63 (2 f64/lane), lanes 32-63 row r+1
    int halfSel = lane >> 5;
    int colSel  = (lane & 31) * 2;
    #define STAGE2(sb, bf, wp, tb, nrows)                                          \
        for (int p = 0; p < (nrows) / 2; ++p) {                                    \
            const double* src = (wp) + (size_t)((tb) + 2 * p + halfSel) * NOUT + colSel; \
            __builtin_amdgcn_global_load_lds(                                      \
                (const __attribute__((address_space(1))) void*)src,                \
                (__attribute__((address_space(3))) void*)(&xbuf[sb][bf][p * 128]), \
                16, 0, 0);                                                         \
        }

    unsigned long long histA = 0ULL, histB = 0ULL;  // bit b <=> spike at t-(b+1)
    int buf = 0;
    STAGE2(0, 0, wpA, 0, 16);
    STAGE2(1, 0, wpB, 0, 16);
    asm volatile("s_waitcnt vmcnt(0)" ::: "memory");
    __syncthreads();

    for (int tb = 0; tb < TT; tb += 16) {
        int nrows = TT - tb; if (nrows > 16) nrows = 16;
        int nnext = TT - (tb + 16); if (nnext > 16) nnext = 16;
        if (nnext > 0) {
            STAGE2(0, buf ^ 1, wpA, tb + 16, nnext);
            STAGE2(1, buf ^ 1, wpB, tb + 16, nnext);
        }
        for (int tl = 0; tl < nrows; ++tl) {
            double xA = xbuf[0][buf][tl * 64 + lane];
            double xB = xbuf[1][buf][tl * 64 + lane];
            unsigned long long hA = histA, hB = histB;
            double RA = (Tb[0][(unsigned)( hA        & 255)] + Tb[1][(unsigned)((hA >>  8) & 255)])
                      + (Tb[2][(unsigned)((hA >> 16) & 255)] + Tb[3][(unsigned)((hA >> 24) & 255)])
                      + (Tb[4][(unsigned)((hA >> 32) & 255)] + Tb[5][(unsigned)((hA >> 40) & 255)])
                      + (Tb[6][(unsigned)((hA >> 48) & 255)] + Tb[7][(unsigned)((hA >> 56) & 255)]);
            double RB = (Tb[0][(unsigned)( hB        & 255)] + Tb[1][(unsigned)((hB >>  8) & 255)])
                      + (Tb[2][(unsigned)((hB >> 16) & 255)] + Tb[3][(unsigned)((hB >> 24) & 255)])
                      + (Tb[4][(unsigned)((hB >> 32) & 255)] + Tb[5][(unsigned)((hB >> 40) & 255)])
                      + (Tb[6][(unsigned)((hB >> 48) & 255)] + Tb[7][(unsigned)((hB >> 56) & 255)]);
            bool spA = (xA + RA >= 10.0);
            bool spB = (xB + RB >= 10.0);
            histA = ((histA << 1) | (unsigned long long)spA) & 0x7FFFFFFFFFFFFFFFULL;
            histB = ((histB << 1) | (unsigned long long)spB) & 0x7FFFFFFFFFFFFFFFULL;
            obuf[0][lane * 17 + tl] = spA ? 1.0f : 0.0f;
            obuf[1][lane * 17 + tl] = spB ? 1.0f : 0.0f;
        }
        for (int k = 0; k + 3 < nrows; k += 4) {
            float4 vA = make_float4(obuf[0][lane * 17 + k],     obuf[0][lane * 17 + k + 1],
                                    obuf[0][lane * 17 + k + 2], obuf[0][lane * 17 + k + 3]);
            float4 vB = make_float4(obuf[1][lane * 17 + k],     obuf[1][lane * 17 + k + 1],
                                    obuf[1][lane * 17 + k + 2], obuf[1][lane * 17 + k + 3]);
            *(float4*)(opA + tb + k) = vA;
            *(float4*)(opB + tb + k) = vB;
        }
        asm volatile("s_waitcnt vmcnt(0)" ::: "memory");
        __syncthreads();
        buf ^= 1;
    }
    #undef STAGE2
}

extern "C" void kernel_launch(void* const* d_in, const int* in_sizes, int n_in,
                              void* d_out, int out_size, void* d_ws, size_t ws_size,
                              hipStream_t stream) {
    const float* spikeInput = (const float*)d_in[0];   // [16][2048][1000]
    const float* weight     = (const float*)d_in[1];   // [512][2048]
    float* out = (float*)d_out;                        // [16][512][1000]

    char* ws = (char*)d_ws;
    unsigned long long* bits = (unsigned long long*)ws;            //  4,096,000 B
    float*              WT   = (float*)(ws + 4194304);             //  4,194,304 B
    double*             z    = (double*)(ws + 8388608);            // 65,536,000 B
    double*             wpsp = (double*)(ws + 73924608);           // 65,536,000 B
    // total: 139,460,608 B

    k_transpose<<<(NIN * NOUT) / 256, 256, 0, stream>>>(weight, WT);
    k_extract<<<dim3(16, 32, 16), 256, 0, stream>>>(spikeInput, bits);
    k_spmm<<<NB * TT, 128, 0, stream>>>(bits, WT, z);
    k_conv<<<dim3(32, 4, 16), 128, 0, stream>>>(z, wpsp);
    k_scan<<<64, 64, 0, stream>>>(wpsp, out);
}

// Round 7
// 712.889 us; speedup vs baseline: 1.2128x; 1.2128x over previous
//
#include <hip/hip_runtime.h>
#include <hip/hip_bf16.h>
#include <math.h>

#define NB 16
#define NIN 2048
#define NOUT 512
#define TT 1000
#define L_SRM 31
#define CAP2 768

// ---------------- kernel 1: transpose W [512][2048] -> WT [2048][512] ----------
__global__ void k_transpose(const float* __restrict__ W, float* __restrict__ WT) {
    int idx = blockIdx.x * 256 + threadIdx.x;   // over 2048*512
    int i = idx >> 9;        // input channel
    int o = idx & 511;       // output channel
    WT[idx] = W[o * NIN + i];
}

// ---------------- kernel 2: ballot-transpose spike extract --------------------
// block 256 thr = 4 waves. Tile: 64 inputs x 64 timesteps. No atomics.
// out: bits[n][t][ic] (u64), bit b of word ic <=> input i = ic*64+b active at t.
__global__ __launch_bounds__(256) void k_extract(const float* __restrict__ s,
                                                 unsigned long long* __restrict__ bits) {
    __shared__ float tile[64][65];          // padded: column reads conflict-free
    int tc = blockIdx.x;                    // t-chunk (16)
    int ic = blockIdx.y;                    // i-chunk (32)
    int n  = blockIdx.z;                    // batch (16)
    int t0 = tc * 64, i0 = ic * 64;
    int tid = threadIdx.x;
    int r   = tid >> 2;                     // tile row (input)
    int cq  = tid & 3;                      // col quarter
    const float* rp = s + ((size_t)(n * NIN + i0 + r)) * TT + t0;
    #pragma unroll
    for (int q = 0; q < 4; ++q) {
        int col = cq * 16 + q * 4;
        float4 v = make_float4(0.f, 0.f, 0.f, 0.f);
        if (t0 + col + 3 < TT) v = *(const float4*)(rp + col);
        tile[r][col]     = v.x;
        tile[r][col + 1] = v.y;
        tile[r][col + 2] = v.z;
        tile[r][col + 3] = v.w;
    }
    __syncthreads();
    int lane = tid & 63;
    int w    = tid >> 6;
    #pragma unroll
    for (int k = 0; k < 16; ++k) {
        int tl = w * 16 + k;
        if (t0 + tl >= TT) break;
        float val = tile[lane][tl];
        unsigned long long m = __ballot(val != 0.0f);
        if (lane == 0)
            bits[((size_t)n * TT + t0 + tl) * 32 + ic] = m;
    }
}

// ---------------- kernel 3: sparse accumulate z[n][t][o] = sum_{active i} WT[i][o]
// 128 threads/block, each thread owns 4 outputs (float4 row loads).
// f64 accumulation (exact ~1e-13); nontemporal z stores keep WT in L2.
__global__ __launch_bounds__(128) void k_spmm(const unsigned long long* __restrict__ bits,
                                              const float* __restrict__ WT,
                                              double* __restrict__ z) {
    int nt  = blockIdx.x;       // 0 .. NB*TT-1
    int tid = threadIdx.x;      // 128
    __shared__ int sidx[CAP2];  // active rows as element offsets (idx*512)
    __shared__ int s_cnt;
    if (tid < 64) {             // wave 0 compacts 32 bitmask words -> offset list
        unsigned long long w = (tid < 32) ? bits[(size_t)nt * 32 + tid] : 0ULL;
        int pc  = __popcll(w);
        int pre = pc;
        #pragma unroll
        for (int d = 1; d < 32; d <<= 1) {
            int x = __shfl_up(pre, d, 64);
            if (tid >= d) pre += x;
        }
        pre -= pc;              // exclusive prefix
        if (tid == 31) s_cnt = pre + pc;
        int base = tid * 64;
        while (w) {
            int b = __builtin_ctzll(w);
            if (pre < CAP2) sidx[pre] = (base + b) << 9;    // * NOUT
            ++pre;
            w &= w - 1;
        }
    }
    __syncthreads();
    int c = s_cnt;
    if (c > CAP2) c = CAP2;
    const float* wp = WT + (tid << 2);      // this thread's 4-output column
    double a0 = 0., a1 = 0., a2 = 0., a3 = 0.;
    double b0 = 0., b1 = 0., b2 = 0., b3 = 0.;
    int j = 0;
    for (; j + 1 < c; j += 2) {
        float4 u = *(const float4*)(wp + sidx[j]);
        float4 v = *(const float4*)(wp + sidx[j + 1]);
        a0 += (double)u.x; a1 += (double)u.y; a2 += (double)u.z; a3 += (double)u.w;
        b0 += (double)v.x; b1 += (double)v.y; b2 += (double)v.z; b3 += (double)v.w;
    }
    if (j < c) {
        float4 u = *(const float4*)(wp + sidx[j]);
        a0 += (double)u.x; a1 += (double)u.y; a2 += (double)u.z; a3 += (double)u.w;
    }
    double* zp = &z[(size_t)nt * NOUT + (tid << 2)];
    __builtin_nontemporal_store(a0 + b0, zp);
    __builtin_nontemporal_store(a1 + b1, zp + 1);
    __builtin_nontemporal_store(a2 + b2, zp + 2);
    __builtin_nontemporal_store(a3 + b3, zp + 3);
}

// ---------------- kernel 4: temporal conv wpsp[n][t][o] = sum_j srm[j]*z[n][t-j][o]
// block: 128 threads (one 128-o chunk); t-chunk 32, halo 30 -> 62 rows.
// LDS = 62*128*8 = 63488 B (< 64 KB).
__global__ __launch_bounds__(128) void k_conv(const double* __restrict__ z,
                                              double* __restrict__ wpsp) {
    __shared__ float srm_s[32];
    __shared__ double zs[62 * 128];
    int tid = threadIdx.x;
    if (tid < L_SRM) {
        // match np: f64 alpha samples cast to f32 (SRM_KERNEL values)
        double t = (double)tid;
        srm_s[tid] = (float)((t / 4.0) * exp(1.0 - t / 4.0));   // * TS(=1)
    }
    int tb = blockIdx.x * 32;
    int oc = blockIdx.y * 128;
    int n  = blockIdx.z;
    const double* zp = z + ((size_t)n * TT) * NOUT + oc;
    for (int r = 0; r < 62; ++r) {
        int t = tb - 30 + r;
        zs[r * 128 + tid] = (t >= 0 && t < TT) ? zp[(size_t)t * NOUT + tid] : 0.0;
    }
    __syncthreads();
    for (int tl = 0; tl < 32; ++tl) {
        int t = tb + tl;
        if (t >= TT) break;
        double acc = 0.0;
        #pragma unroll
        for (int jj = 0; jj < L_SRM; ++jj)
            acc += (double)srm_s[jj] * zs[(tl + 30 - jj) * 128 + tid];
        wpsp[((size_t)n * TT + t) * NOUT + oc + tid] = acc;
    }
}

// ---------------- kernel 5: spike scan v3 — speculative 1-step lookahead ------
// block: 64 threads (1 wave) = one n, one 64-wide o-chunk; 128 blocks.
// Per step, the table lookups for step t+1 are issued BEFORE spike_t resolves:
// bytes 1..7 of hist_{t+1} depend only on hist_t; byte 0 has one unknown bit ->
// two candidate lookups, selected by cndmask when spike_t is known. Critical
// path per step = sel + f64 add + f64 cmp; LDS latency pipelines 1 step deep.
__global__ __launch_bounds__(64) void k_scan(const double* __restrict__ wpsp,
                                             float* __restrict__ out) {
    __shared__ float  refTab[64];                       // f32 REF_KERNEL values
    __shared__ double Tb[8][256];                       // byte partial sums, 16 KB
    __shared__ __align__(16) double xbuf[2][33 * 64];   // 32 rows + 1 pad row
    __shared__ float  obuf[64 * 33];                    // output stage [o][t], padded
    int lane = threadIdx.x;
    {
        double d = (double)lane;
        refTab[lane] = (lane == 0) ? 0.0f
                     : (float)(-20.0 * (d / 4.0) * exp(1.0 - d / 4.0));
    }
    __syncthreads();
    for (int e = lane; e < 2048; e += 64) {
        int k = e >> 8, m = e & 255;
        double s = 0.0;
        #pragma unroll
        for (int j = 0; j < 8; ++j) {
            int idx = 8 * k + j + 1;
            if (((m >> j) & 1) && idx <= 63) s += (double)refTab[idx];
        }
        Tb[k][m] = s;
    }

    int n  = blockIdx.x >> 3;
    int o0 = (blockIdx.x & 7) << 6;
    const double* wp = wpsp + ((size_t)n * TT) * NOUT + o0;
    float* op = out + ((size_t)(n * NOUT) + o0 + lane) * TT;

    // stage nrows rows (64 f64 each) starting at row tb into xbuf[buf]:
    // 2 rows/issue: lanes 0-31 row r cols 0..63 (16B/lane), lanes 32-63 row r+1
    int halfSel = lane >> 5;
    int colSel  = (lane & 31) * 2;
    #define STAGE(bf, tb, nrows)                                                   \
        for (int p = 0; p < (nrows) / 2; ++p) {                                    \
            const double* src = wp + (size_t)((tb) + 2 * p + halfSel) * NOUT + colSel; \
            __builtin_amdgcn_global_load_lds(                                      \
                (const __attribute__((address_space(1))) void*)src,                \
                (__attribute__((address_space(3))) void*)(&xbuf[bf][p * 128]),     \
                16, 0, 0);                                                         \
        }

    unsigned long long hist = 0ULL;     // bit b set <=> spike at t-(b+1)
    bool sp = false;                    // spike at previous step
    int buf = 0;
    STAGE(0, 0, 32);
    asm volatile("s_waitcnt vmcnt(0)" ::: "memory");
    __syncthreads();

    double x = xbuf[0][lane];           // x_{t=0}
    double partial = 0.0;               // sum of byte1..7 lookups for t=0 (hist=0)
    double c0 = 0.0, c1 = Tb[0][1];     // byte0 candidates for t=0

    for (int tb = 0; tb < TT; tb += 32) {
        int nnext = TT - (tb + 32); if (nnext > 32) nnext = 32;
        if (nnext > 0) { STAGE(buf ^ 1, tb + 32, nnext); }
        #pragma unroll
        for (int tl = 0; tl < 32; ++tl) {
            // 1. commit history with previous spike (off critical path)
            hist = ((hist << 1) | (unsigned long long)sp) & 0x7FFFFFFFFFFFFFFFULL;
            // 2. speculative issue for NEXT step (independent of this step's spike)
            unsigned long long hs = (hist << 1) & 0x7FFFFFFFFFFFFFFFULL;
            double T1 = Tb[1][(unsigned)((hs >>  8) & 255)];
            double T2 = Tb[2][(unsigned)((hs >> 16) & 255)];
            double T3 = Tb[3][(unsigned)((hs >> 24) & 255)];
            double T4 = Tb[4][(unsigned)((hs >> 32) & 255)];
            double T5 = Tb[5][(unsigned)((hs >> 40) & 255)];
            double T6 = Tb[6][(unsigned)((hs >> 48) & 255)];
            double T7 = Tb[7][(unsigned)((hs >> 56) & 255)];
            unsigned m = (unsigned)(hs & 255);
            double nc0 = Tb[0][m];
            double nc1 = Tb[0][m | 1];
            double nx  = xbuf[buf][(tl + 1) * 64 + lane];   // row 32 = pad (safe)
            // 3. resolve current step: sel + add + cmp is the serial chain
            double u = (x + partial) + (sp ? c1 : c0);
            sp = (u >= 10.0);
            obuf[lane * 33 + tl] = sp ? 1.0f : 0.0f;
            // 4. rotate speculative state
            partial = ((T1 + T2) + (T3 + T4)) + ((T5 + T6) + T7);
            c0 = nc0; c1 = nc1; x = nx;
        }
        int nrows = TT - tb; if (nrows > 32) nrows = 32;
        for (int k = 0; k + 3 < nrows; k += 4) {
            float4 v = make_float4(obuf[lane * 33 + k],     obuf[lane * 33 + k + 1],
                                   obuf[lane * 33 + k + 2], obuf[lane * 33 + k + 3]);
            *(float4*)(op + tb + k) = v;
        }
        asm volatile("s_waitcnt vmcnt(0)" ::: "memory");
        __syncthreads();
        buf ^= 1;
        x = xbuf[buf][lane];            // fresh row 0 of the newly staged chunk
    }
    #undef STAGE
}

extern "C" void kernel_launch(void* const* d_in, const int* in_sizes, int n_in,
                              void* d_out, int out_size, void* d_ws, size_t ws_size,
                              hipStream_t stream) {
    const float* spikeInput = (const float*)d_in[0];   // [16][2048][1000]
    const float* weight     = (const float*)d_in[1];   // [512][2048]
    float* out = (float*)d_out;                        // [16][512][1000]

    char* ws = (char*)d_ws;
    unsigned long long* bits = (unsigned long long*)ws;            //  4,096,000 B
    float*              WT   = (float*)(ws + 4194304);             //  4,194,304 B
    double*             z    = (double*)(ws + 8388608);            // 65,536,000 B
    double*             wpsp = (double*)(ws + 73924608);           // 65,536,000 B
    // total: 139,460,608 B

    k_transpose<<<(NIN * NOUT) / 256, 256, 0, stream>>>(weight, WT);
    k_extract<<<dim3(16, 32, 16), 256, 0, stream>>>(spikeInput, bits);
    k_spmm<<<NB * TT, 128, 0, stream>>>(bits, WT, z);
    k_conv<<<dim3(32, 4, 16), 128, 0, stream>>>(z, wpsp);
    k_scan<<<128, 64, 0, stream>>>(wpsp, out);
}

// Round 8
// 563.593 us; speedup vs baseline: 1.5340x; 1.2649x over previous
//
#include <hip/hip_runtime.h>
#include <hip/hip_bf16.h>
#include <math.h>

#define NB 16
#define NIN 2048
#define NOUT 512
#define TT 1000
#define L_SRM 31

typedef int v4i  __attribute__((ext_vector_type(4)));
typedef int v16i __attribute__((ext_vector_type(16)));

// spread 8 bits -> 8 bytes (0/1) in a u64 (little-endian byte i = bit i)
__device__ __forceinline__ unsigned long long spread8(unsigned int b) {
    unsigned long long x = (unsigned long long)(b & 0xFFu) * 0x0101010101010101ULL;
    x &= 0x8040201008040201ULL;
    x |= x >> 4; x |= x >> 2; x |= x >> 1;
    return x & 0x0101010101010101ULL;
}

// ---------------- kernel 1: quantize W -> 4 signed-i8 planes, o-major --------
// w_q = rint(w * 2^29) (i32, exact in f64);  w_q = b3*2^24+b2*2^16+b1*2^8+b0
__global__ __launch_bounds__(256) void k_quant(const float* __restrict__ W,
                                               signed char* __restrict__ Bq) {
    int idx = blockIdx.x * 256 + threadIdx.x;    // over 512*2048
    int o = idx >> 11, i = idx & (NIN - 1);
    double w = (double)W[o * NIN + i];
    int wq = (int)rint(w * 536870912.0);
    int b0 = (int)(signed char)(wq & 255); int r = (wq - b0) >> 8;
    int b1 = (int)(signed char)(r  & 255); r = (r - b1) >> 8;
    int b2 = (int)(signed char)(r  & 255); r = (r - b2) >> 8;
    int b3 = r;                                  // |b3| <= ~65
    size_t e = (size_t)o * NIN + i;
    Bq[e]                = (signed char)b0;
    Bq[e + 1048576]      = (signed char)b1;
    Bq[e + 2097152]      = (signed char)b2;
    Bq[e + 3145728]      = (signed char)b3;
}

// ---------------- kernel 2: ballot-transpose spike extract --------------------
__global__ __launch_bounds__(256) void k_extract(const float* __restrict__ s,
                                                 unsigned long long* __restrict__ bits) {
    __shared__ float tile[64][65];
    int tc = blockIdx.x, ic = blockIdx.y, n = blockIdx.z;
    int t0 = tc * 64, i0 = ic * 64;
    int tid = threadIdx.x;
    int r = tid >> 2, cq = tid & 3;
    const float* rp = s + ((size_t)(n * NIN + i0 + r)) * TT + t0;
    #pragma unroll
    for (int q = 0; q < 4; ++q) {
        int col = cq * 16 + q * 4;
        float4 v = make_float4(0.f, 0.f, 0.f, 0.f);
        if (t0 + col + 3 < TT) v = *(const float4*)(rp + col);
        tile[r][col] = v.x; tile[r][col + 1] = v.y;
        tile[r][col + 2] = v.z; tile[r][col + 3] = v.w;
    }
    __syncthreads();
    int lane = tid & 63, w = tid >> 6;
    #pragma unroll
    for (int k = 0; k < 16; ++k) {
        int tl = w * 16 + k;
        if (t0 + tl >= TT) break;
        unsigned long long m = __ballot(tile[lane][tl] != 0.0f);
        if (lane == 0) bits[((size_t)n * TT + t0 + tl) * 32 + ic] = m;
    }
}

// ---------------- kernel 3: i8-MFMA spike GEMM, 4 exact planes ----------------
// tile 128(nt) x 64(o), 8 waves (4Mx2N of 32x32), K=2048 in 16 steps of 128.
// A from bitmask (spread to i8 in LDS), B planes reg-prefetched then LDS.
// XOR-swizzle ((row&7)<<4) on both LDS write & read (rule: both sides).
__global__ __launch_bounds__(512) void k_spmm(const unsigned long long* __restrict__ bits,
                                              const signed char* __restrict__ Bq,
                                              double* __restrict__ z) {
    __shared__ char Alds[128 * 128];        // 16 KB
    __shared__ char Blds[4][64 * 128];      // 32 KB
    int tid = threadIdx.x;
    int bid = blockIdx.x;                   // 1000
    int o0  = (bid & 7) * 64;               // bid%8 ~ XCD residue: B col-set L2-resident
    int nt0 = (bid >> 3) * 128;

    // staging roles
    const int arow_w = tid >> 2, q = tid & 3;            // A: row, 32-bit quarter
    const int p_st = tid >> 7, orow = (tid >> 1) & 63, h = tid & 1;   // B
    const unsigned int* agp = (const unsigned int*)bits + (size_t)(nt0 + arow_w) * 64 + q;
    const signed char*  bgp = Bq + (size_t)p_st * (NOUT * NIN)
                                 + (size_t)(o0 + orow) * NIN + h * 64;
    char* awp = Alds + arow_w * 128;
    const int xra_w = arow_w & 7;
    char* bwp = Blds[p_st] + orow * 128;
    const int xro_w = orow & 7;

    // compute roles
    const int l = tid & 63, wv = tid >> 6;
    const int wm = wv >> 1, wn = wv & 1;
    const int arow = wm * 32 + (l & 31), xra = arow & 7;
    const int brow = wn * 32 + (l & 31), xrb = brow & 7;
    const int kg = l >> 5;                  // k-group (0/1)

    v16i acc0 = {}, acc1 = {}, acc2 = {}, acc3 = {};

    // prefetch ks=0
    unsigned int aw = agp[0];
    int4 bs0 = ((const int4*)bgp)[0], bs1 = ((const int4*)bgp)[1],
         bs2 = ((const int4*)bgp)[2], bs3 = ((const int4*)bgp)[3];

    for (int ks = 0; ks < 16; ++ks) {
        __syncthreads();
        // write A (bit->byte spread) and B into LDS, swizzled
        {
            unsigned long long s0 = spread8(aw), s1 = spread8(aw >> 8),
                               s2 = spread8(aw >> 16), s3 = spread8(aw >> 24);
            ulonglong2 v0; v0.x = s0; v0.y = s1;
            ulonglong2 v1; v1.x = s2; v1.y = s3;
            *(ulonglong2*)(awp + (((2 * q)     ^ xra_w) << 4)) = v0;
            *(ulonglong2*)(awp + (((2 * q + 1) ^ xra_w) << 4)) = v1;
            *(int4*)(bwp + (((h * 4 + 0) ^ xro_w) << 4)) = bs0;
            *(int4*)(bwp + (((h * 4 + 1) ^ xro_w) << 4)) = bs1;
            *(int4*)(bwp + (((h * 4 + 2) ^ xro_w) << 4)) = bs2;
            *(int4*)(bwp + (((h * 4 + 3) ^ xro_w) << 4)) = bs3;
        }
        __syncthreads();
        if (ks < 15) {                      // T14: issue next-step loads early
            aw = agp[(ks + 1) * 4];
            const int4* g = (const int4*)(bgp + (size_t)(ks + 1) * 128);
            bs0 = g[0]; bs1 = g[1]; bs2 = g[2]; bs3 = g[3];
        }
        #pragma unroll
        for (int ksub = 0; ksub < 4; ++ksub) {
            int ca = ksub * 2 + kg;
            v4i av  = *(const v4i*)(Alds    + arow * 128 + (((ca) ^ xra) << 4));
            v4i bv0 = *(const v4i*)(Blds[0] + brow * 128 + (((ca) ^ xrb) << 4));
            v4i bv1 = *(const v4i*)(Blds[1] + brow * 128 + (((ca) ^ xrb) << 4));
            v4i bv2 = *(const v4i*)(Blds[2] + brow * 128 + (((ca) ^ xrb) << 4));
            v4i bv3 = *(const v4i*)(Blds[3] + brow * 128 + (((ca) ^ xrb) << 4));
            acc0 = __builtin_amdgcn_mfma_i32_32x32x32_i8(av, bv0, acc0, 0, 0, 0);
            acc1 = __builtin_amdgcn_mfma_i32_32x32x32_i8(av, bv1, acc1, 0, 0, 0);
            acc2 = __builtin_amdgcn_mfma_i32_32x32x32_i8(av, bv2, acc2, 0, 0, 0);
            acc3 = __builtin_amdgcn_mfma_i32_32x32x32_i8(av, bv3, acc3, 0, 0, 0);
        }
    }

    // epilogue: exact reconstruction, f64 (C/D layout verified m74/m101)
    #pragma unroll
    for (int r = 0; r < 16; ++r) {
        int row = (r & 3) + 8 * (r >> 2) + 4 * kg;
        long long tot = ((long long)acc3[r] << 24) + ((long long)acc2[r] << 16)
                      + ((long long)acc1[r] << 8)  +  (long long)acc0[r];
        double zv = (double)tot * (1.0 / 536870912.0);
        __builtin_nontemporal_store(zv,
            &z[(size_t)(nt0 + wm * 32 + row) * NOUT + (o0 + wn * 32 + (l & 31))]);
    }
}

// ---------------- kernel 4: temporal conv (unchanged, f64) --------------------
__global__ __launch_bounds__(128) void k_conv(const double* __restrict__ z,
                                              double* __restrict__ wpsp) {
    __shared__ float srm_s[32];
    __shared__ double zs[62 * 128];
    int tid = threadIdx.x;
    if (tid < L_SRM) {
        double t = (double)tid;
        srm_s[tid] = (float)((t / 4.0) * exp(1.0 - t / 4.0));
    }
    int tb = blockIdx.x * 32;
    int oc = blockIdx.y * 128;
    int n  = blockIdx.z;
    const double* zp = z + ((size_t)n * TT) * NOUT + oc;
    for (int r = 0; r < 62; ++r) {
        int t = tb - 30 + r;
        zs[r * 128 + tid] = (t >= 0 && t < TT) ? zp[(size_t)t * NOUT + tid] : 0.0;
    }
    __syncthreads();
    for (int tl = 0; tl < 32; ++tl) {
        int t = tb + tl;
        if (t >= TT) break;
        double acc = 0.0;
        #pragma unroll
        for (int jj = 0; jj < L_SRM; ++jj)
            acc += (double)srm_s[jj] * zs[(tl + 30 - jj) * 128 + tid];
        wpsp[((size_t)n * TT + t) * NOUT + oc + tid] = acc;
    }
}

// ---------------- kernel 5: spike scan v3 (unchanged, speculative lookahead) --
__global__ __launch_bounds__(64) void k_scan(const double* __restrict__ wpsp,
                                             float* __restrict__ out) {
    __shared__ float  refTab[64];
    __shared__ double Tb[8][256];
    __shared__ __align__(16) double xbuf[2][33 * 64];
    __shared__ float  obuf[64 * 33];
    int lane = threadIdx.x;
    {
        double d = (double)lane;
        refTab[lane] = (lane == 0) ? 0.0f
                     : (float)(-20.0 * (d / 4.0) * exp(1.0 - d / 4.0));
    }
    __syncthreads();
    for (int e = lane; e < 2048; e += 64) {
        int k = e >> 8, m = e & 255;
        double s = 0.0;
        #pragma unroll
        for (int j = 0; j < 8; ++j) {
            int idx = 8 * k + j + 1;
            if (((m >> j) & 1) && idx <= 63) s += (double)refTab[idx];
        }
        Tb[k][m] = s;
    }

    int n  = blockIdx.x >> 3;
    int o0 = (blockIdx.x & 7) << 6;
    const double* wp = wpsp + ((size_t)n * TT) * NOUT + o0;
    float* op = out + ((size_t)(n * NOUT) + o0 + lane) * TT;

    int halfSel = lane >> 5;
    int colSel  = (lane & 31) * 2;
    #define STAGE(bf, tb, nrows)                                                   \
        for (int p = 0; p < (nrows) / 2; ++p) {                                    \
            const double* src = wp + (size_t)((tb) + 2 * p + halfSel) * NOUT + colSel; \
            __builtin_amdgcn_global_load_lds(                                      \
                (const __attribute__((address_space(1))) void*)src,                \
                (__attribute__((address_space(3))) void*)(&xbuf[bf][p * 128]),     \
                16, 0, 0);                                                         \
        }

    unsigned long long hist = 0ULL;
    bool sp = false;
    int buf = 0;
    STAGE(0, 0, 32);
    asm volatile("s_waitcnt vmcnt(0)" ::: "memory");
    __syncthreads();

    double x = xbuf[0][lane];
    double partial = 0.0;
    double c0 = 0.0, c1 = Tb[0][1];

    for (int tb = 0; tb < TT; tb += 32) {
        int nnext = TT - (tb + 32); if (nnext > 32) nnext = 32;
        if (nnext > 0) { STAGE(buf ^ 1, tb + 32, nnext); }
        #pragma unroll
        for (int tl = 0; tl < 32; ++tl) {
            hist = ((hist << 1) | (unsigned long long)sp) & 0x7FFFFFFFFFFFFFFFULL;
            unsigned long long hs = (hist << 1) & 0x7FFFFFFFFFFFFFFFULL;
            double T1 = Tb[1][(unsigned)((hs >>  8) & 255)];
            double T2 = Tb[2][(unsigned)((hs >> 16) & 255)];
            double T3 = Tb[3][(unsigned)((hs >> 24) & 255)];
            double T4 = Tb[4][(unsigned)((hs >> 32) & 255)];
            double T5 = Tb[5][(unsigned)((hs >> 40) & 255)];
            double T6 = Tb[6][(unsigned)((hs >> 48) & 255)];
            double T7 = Tb[7][(unsigned)((hs >> 56) & 255)];
            unsigned m = (unsigned)(hs & 255);
            double nc0 = Tb[0][m];
            double nc1 = Tb[0][m | 1];
            double nx  = xbuf[buf][(tl + 1) * 64 + lane];
            double u = (x + partial) + (sp ? c1 : c0);
            sp = (u >= 10.0);
            obuf[lane * 33 + tl] = sp ? 1.0f : 0.0f;
            partial = ((T1 + T2) + (T3 + T4)) + ((T5 + T6) + T7);
            c0 = nc0; c1 = nc1; x = nx;
        }
        int nrows = TT - tb; if (nrows > 32) nrows = 32;
        for (int k = 0; k + 3 < nrows; k += 4) {
            float4 v = make_float4(obuf[lane * 33 + k],     obuf[lane * 33 + k + 1],
                                   obuf[lane * 33 + k + 2], obuf[lane * 33 + k + 3]);
            *(float4*)(op + tb + k) = v;
        }
        asm volatile("s_waitcnt vmcnt(0)" ::: "memory");
        __syncthreads();
        buf ^= 1;
        x = xbuf[buf][lane];
    }
    #undef STAGE
}

extern "C" void kernel_launch(void* const* d_in, const int* in_sizes, int n_in,
                              void* d_out, int out_size, void* d_ws, size_t ws_size,
                              hipStream_t stream) {
    const float* spikeInput = (const float*)d_in[0];   // [16][2048][1000]
    const float* weight     = (const float*)d_in[1];   // [512][2048]
    float* out = (float*)d_out;                        // [16][512][1000]

    char* ws = (char*)d_ws;
    unsigned long long* bits = (unsigned long long*)ws;            //  4,096,000 B
    signed char*        Bq   = (signed char*)(ws + 4194304);       //  4,194,304 B
    double*             z    = (double*)(ws + 8388608);            // 65,536,000 B
    double*             wpsp = (double*)(ws + 73924608);           // 65,536,000 B

    k_quant<<<(NOUT * NIN) / 256, 256, 0, stream>>>(weight, Bq);
    k_extract<<<dim3(16, 32, 16), 256, 0, stream>>>(spikeInput, bits);
    k_spmm<<<1000, 512, 0, stream>>>(bits, Bq, z);
    k_conv<<<dim3(32, 4, 16), 128, 0, stream>>>(z, wpsp);
    k_scan<<<128, 64, 0, stream>>>(wpsp, out);
}

// Round 9
// 485.560 us; speedup vs baseline: 1.7806x; 1.1607x over previous
//
#include <hip/hip_runtime.h>
#include <hip/hip_bf16.h>
#include <math.h>

#define NB 16
#define NIN 2048
#define NOUT 512
#define TT 1000
#define L_SRM 31

typedef int v4i  __attribute__((ext_vector_type(4)));
typedef int v16i __attribute__((ext_vector_type(16)));

// spread 8 bits -> 8 bytes (0/1) in a u64 (little-endian byte i = bit i)
__device__ __forceinline__ unsigned long long spread8(unsigned int b) {
    unsigned long long x = (unsigned long long)(b & 0xFFu) * 0x0101010101010101ULL;
    x &= 0x8040201008040201ULL;
    x |= x >> 4; x |= x >> 2; x |= x >> 1;
    return x & 0x0101010101010101ULL;
}

// ---------------- kernel 1: quantize W -> 4 signed-i8 planes, o-major --------
// w_q = rint(w * 2^29) (i32, exact in f64);  w_q = b3*2^24+b2*2^16+b1*2^8+b0
__global__ __launch_bounds__(256) void k_quant(const float* __restrict__ W,
                                               signed char* __restrict__ Bq) {
    int idx = blockIdx.x * 256 + threadIdx.x;    // over 512*2048
    int o = idx >> 11, i = idx & (NIN - 1);
    double w = (double)W[o * NIN + i];
    int wq = (int)rint(w * 536870912.0);
    int b0 = (int)(signed char)(wq & 255); int r = (wq - b0) >> 8;
    int b1 = (int)(signed char)(r  & 255); r = (r - b1) >> 8;
    int b2 = (int)(signed char)(r  & 255); r = (r - b2) >> 8;
    int b3 = r;                                  // |b3| <= ~65
    size_t e = (size_t)o * NIN + i;
    Bq[e]                = (signed char)b0;
    Bq[e + 1048576]      = (signed char)b1;
    Bq[e + 2097152]      = (signed char)b2;
    Bq[e + 3145728]      = (signed char)b3;
}

// ---------------- kernel 2: ballot-transpose spike extract --------------------
__global__ __launch_bounds__(256) void k_extract(const float* __restrict__ s,
                                                 unsigned long long* __restrict__ bits) {
    __shared__ float tile[64][65];
    int tc = blockIdx.x, ic = blockIdx.y, n = blockIdx.z;
    int t0 = tc * 64, i0 = ic * 64;
    int tid = threadIdx.x;
    int r = tid >> 2, cq = tid & 3;
    const float* rp = s + ((size_t)(n * NIN + i0 + r)) * TT + t0;
    #pragma unroll
    for (int q = 0; q < 4; ++q) {
        int col = cq * 16 + q * 4;
        float4 v = make_float4(0.f, 0.f, 0.f, 0.f);
        if (t0 + col + 3 < TT) v = *(const float4*)(rp + col);
        tile[r][col] = v.x; tile[r][col + 1] = v.y;
        tile[r][col + 2] = v.z; tile[r][col + 3] = v.w;
    }
    __syncthreads();
    int lane = tid & 63, w = tid >> 6;
    #pragma unroll
    for (int k = 0; k < 16; ++k) {
        int tl = w * 16 + k;
        if (t0 + tl >= TT) break;
        unsigned long long m = __ballot(tile[lane][tl] != 0.0f);
        if (lane == 0) bits[((size_t)n * TT + t0 + tl) * 32 + ic] = m;
    }
}

// ---------------- kernel 3: i8-MFMA spike GEMM, 4 exact planes ----------------
// tile 128(nt) x 64(o), 8 waves (4Mx2N of 32x32), K=2048 in 16 steps of 128.
__global__ __launch_bounds__(512) void k_spmm(const unsigned long long* __restrict__ bits,
                                              const signed char* __restrict__ Bq,
                                              double* __restrict__ z) {
    __shared__ char Alds[128 * 128];        // 16 KB
    __shared__ char Blds[4][64 * 128];      // 32 KB
    int tid = threadIdx.x;
    int bid = blockIdx.x;                   // 1000
    int o0  = (bid & 7) * 64;               // bid%8 ~ XCD residue: B col-set L2-resident
    int nt0 = (bid >> 3) * 128;

    // staging roles
    const int arow_w = tid >> 2, q = tid & 3;            // A: row, 32-bit quarter
    const int p_st = tid >> 7, orow = (tid >> 1) & 63, h = tid & 1;   // B
    const unsigned int* agp = (const unsigned int*)bits + (size_t)(nt0 + arow_w) * 64 + q;
    const signed char*  bgp = Bq + (size_t)p_st * (NOUT * NIN)
                                 + (size_t)(o0 + orow) * NIN + h * 64;
    char* awp = Alds + arow_w * 128;
    const int xra_w = arow_w & 7;
    char* bwp = Blds[p_st] + orow * 128;
    const int xro_w = orow & 7;

    // compute roles
    const int l = tid & 63, wv = tid >> 6;
    const int wm = wv >> 1, wn = wv & 1;
    const int arow = wm * 32 + (l & 31), xra = arow & 7;
    const int brow = wn * 32 + (l & 31), xrb = brow & 7;
    const int kg = l >> 5;                  // k-group (0/1)

    v16i acc0 = {}, acc1 = {}, acc2 = {}, acc3 = {};

    // prefetch ks=0
    unsigned int aw = agp[0];
    int4 bs0 = ((const int4*)bgp)[0], bs1 = ((const int4*)bgp)[1],
         bs2 = ((const int4*)bgp)[2], bs3 = ((const int4*)bgp)[3];

    for (int ks = 0; ks < 16; ++ks) {
        __syncthreads();
        {
            unsigned long long s0 = spread8(aw), s1 = spread8(aw >> 8),
                               s2 = spread8(aw >> 16), s3 = spread8(aw >> 24);
            ulonglong2 v0; v0.x = s0; v0.y = s1;
            ulonglong2 v1; v1.x = s2; v1.y = s3;
            *(ulonglong2*)(awp + (((2 * q)     ^ xra_w) << 4)) = v0;
            *(ulonglong2*)(awp + (((2 * q + 1) ^ xra_w) << 4)) = v1;
            *(int4*)(bwp + (((h * 4 + 0) ^ xro_w) << 4)) = bs0;
            *(int4*)(bwp + (((h * 4 + 1) ^ xro_w) << 4)) = bs1;
            *(int4*)(bwp + (((h * 4 + 2) ^ xro_w) << 4)) = bs2;
            *(int4*)(bwp + (((h * 4 + 3) ^ xro_w) << 4)) = bs3;
        }
        __syncthreads();
        if (ks < 15) {                      // T14: issue next-step loads early
            aw = agp[(ks + 1) * 4];
            const int4* g = (const int4*)(bgp + (size_t)(ks + 1) * 128);
            bs0 = g[0]; bs1 = g[1]; bs2 = g[2]; bs3 = g[3];
        }
        #pragma unroll
        for (int ksub = 0; ksub < 4; ++ksub) {
            int ca = ksub * 2 + kg;
            v4i av  = *(const v4i*)(Alds    + arow * 128 + (((ca) ^ xra) << 4));
            v4i bv0 = *(const v4i*)(Blds[0] + brow * 128 + (((ca) ^ xrb) << 4));
            v4i bv1 = *(const v4i*)(Blds[1] + brow * 128 + (((ca) ^ xrb) << 4));
            v4i bv2 = *(const v4i*)(Blds[2] + brow * 128 + (((ca) ^ xrb) << 4));
            v4i bv3 = *(const v4i*)(Blds[3] + brow * 128 + (((ca) ^ xrb) << 4));
            acc0 = __builtin_amdgcn_mfma_i32_32x32x32_i8(av, bv0, acc0, 0, 0, 0);
            acc1 = __builtin_amdgcn_mfma_i32_32x32x32_i8(av, bv1, acc1, 0, 0, 0);
            acc2 = __builtin_amdgcn_mfma_i32_32x32x32_i8(av, bv2, acc2, 0, 0, 0);
            acc3 = __builtin_amdgcn_mfma_i32_32x32x32_i8(av, bv3, acc3, 0, 0, 0);
        }
    }

    #pragma unroll
    for (int r = 0; r < 16; ++r) {
        int row = (r & 3) + 8 * (r >> 2) + 4 * kg;
        long long tot = ((long long)acc3[r] << 24) + ((long long)acc2[r] << 16)
                      + ((long long)acc1[r] << 8)  +  (long long)acc0[r];
        double zv = (double)tot * (1.0 / 536870912.0);
        __builtin_nontemporal_store(zv,
            &z[(size_t)(nt0 + wm * 32 + row) * NOUT + (o0 + wn * 32 + (l & 31))]);
    }
}

// ---------------- kernel 4: temporal conv v2 — async LDS staging --------------
// block 128 thr, tile t=32 o=128, halo 30 -> 62 rows. One global_load_lds per
// row (64 lanes x 16B = full 1KB row), single vmcnt(0) drain; boundary rows
// zero-filled via LDS stores (wave-uniform branch). 4-way split FMA chains.
__global__ __launch_bounds__(128) void k_conv(const double* __restrict__ z,
                                              double* __restrict__ wpsp) {
    __shared__ float srm_s[32];
    __shared__ __align__(16) double zs[62 * 128];
    int tid = threadIdx.x;
    if (tid < L_SRM) {
        double t = (double)tid;
        srm_s[tid] = (float)((t / 4.0) * exp(1.0 - t / 4.0));   // * TS(=1)
    }
    int tb = blockIdx.x * 32;
    int oc = blockIdx.y * 128;
    int n  = blockIdx.z;
    const double* zp = z + ((size_t)n * TT) * NOUT + oc;
    int wv = tid >> 6, lane = tid & 63;
    for (int r = wv; r < 62; r += 2) {          // wave-uniform per iteration
        int t = tb - 30 + r;
        if (t >= 0 && t < TT) {
            const double* src = zp + (size_t)t * NOUT + lane * 2;
            __builtin_amdgcn_global_load_lds(
                (const __attribute__((address_space(1))) void*)src,
                (__attribute__((address_space(3))) void*)(&zs[r * 128]),
                16, 0, 0);
        } else {
            double2 zero; zero.x = 0.0; zero.y = 0.0;
            *(double2*)(&zs[r * 128 + lane * 2]) = zero;
        }
    }
    asm volatile("s_waitcnt vmcnt(0)" ::: "memory");
    __syncthreads();
    for (int tl = 0; tl < 32; ++tl) {
        int t = tb + tl;
        if (t >= TT) break;
        double a0 = 0., a1 = 0., a2 = 0., a3 = 0.;
        #pragma unroll
        for (int jj = 0; jj < 28; jj += 4) {
            a0 += (double)srm_s[jj]     * zs[(tl + 30 - jj) * 128 + tid];
            a1 += (double)srm_s[jj + 1] * zs[(tl + 29 - jj) * 128 + tid];
            a2 += (double)srm_s[jj + 2] * zs[(tl + 28 - jj) * 128 + tid];
            a3 += (double)srm_s[jj + 3] * zs[(tl + 27 - jj) * 128 + tid];
        }
        a0 += (double)srm_s[28] * zs[(tl + 2) * 128 + tid];
        a1 += (double)srm_s[29] * zs[(tl + 1) * 128 + tid];
        a2 += (double)srm_s[30] * zs[(tl + 0) * 128 + tid];
        wpsp[((size_t)n * TT + t) * NOUT + oc + tid] = (a0 + a1) + (a2 + a3);
    }
}

// ---------------- kernel 5: spike scan v3 (unchanged, speculative lookahead) --
__global__ __launch_bounds__(64) void k_scan(const double* __restrict__ wpsp,
                                             float* __restrict__ out) {
    __shared__ float  refTab[64];
    __shared__ double Tb[8][256];
    __shared__ __align__(16) double xbuf[2][33 * 64];
    __shared__ float  obuf[64 * 33];
    int lane = threadIdx.x;
    {
        double d = (double)lane;
        refTab[lane] = (lane == 0) ? 0.0f
                     : (float)(-20.0 * (d / 4.0) * exp(1.0 - d / 4.0));
    }
    __syncthreads();
    for (int e = lane; e < 2048; e += 64) {
        int k = e >> 8, m = e & 255;
        double s = 0.0;
        #pragma unroll
        for (int j = 0; j < 8; ++j) {
            int idx = 8 * k + j + 1;
            if (((m >> j) & 1) && idx <= 63) s += (double)refTab[idx];
        }
        Tb[k][m] = s;
    }

    int n  = blockIdx.x >> 3;
    int o0 = (blockIdx.x & 7) << 6;
    const double* wp = wpsp + ((size_t)n * TT) * NOUT + o0;
    float* op = out + ((size_t)(n * NOUT) + o0 + lane) * TT;

    int halfSel = lane >> 5;
    int colSel  = (lane & 31) * 2;
    #define STAGE(bf, tb, nrows)                                                   \
        for (int p = 0; p < (nrows) / 2; ++p) {                                    \
            const double* src = wp + (size_t)((tb) + 2 * p + halfSel) * NOUT + colSel; \
            __builtin_amdgcn_global_load_lds(                                      \
                (const __attribute__((address_space(1))) void*)src,                \
                (__attribute__((address_space(3))) void*)(&xbuf[bf][p * 128]),     \
                16, 0, 0);                                                         \
        }

    unsigned long long hist = 0ULL;
    bool sp = false;
    int buf = 0;
    STAGE(0, 0, 32);
    asm volatile("s_waitcnt vmcnt(0)" ::: "memory");
    __syncthreads();

    double x = xbuf[0][lane];
    double partial = 0.0;
    double c0 = 0.0, c1 = Tb[0][1];

    for (int tb = 0; tb < TT; tb += 32) {
        int nnext = TT - (tb + 32); if (nnext > 32) nnext = 32;
        if (nnext > 0) { STAGE(buf ^ 1, tb + 32, nnext); }
        #pragma unroll
        for (int tl = 0; tl < 32; ++tl) {
            hist = ((hist << 1) | (unsigned long long)sp) & 0x7FFFFFFFFFFFFFFFULL;
            unsigned long long hs = (hist << 1) & 0x7FFFFFFFFFFFFFFFULL;
            double T1 = Tb[1][(unsigned)((hs >>  8) & 255)];
            double T2 = Tb[2][(unsigned)((hs >> 16) & 255)];
            double T3 = Tb[3][(unsigned)((hs >> 24) & 255)];
            double T4 = Tb[4][(unsigned)((hs >> 32) & 255)];
            double T5 = Tb[5][(unsigned)((hs >> 40) & 255)];
            double T6 = Tb[6][(unsigned)((hs >> 48) & 255)];
            double T7 = Tb[7][(unsigned)((hs >> 56) & 255)];
            unsigned m = (unsigned)(hs & 255);
            double nc0 = Tb[0][m];
            double nc1 = Tb[0][m | 1];
            double nx  = xbuf[buf][(tl + 1) * 64 + lane];
            double u = (x + partial) + (sp ? c1 : c0);
            sp = (u >= 10.0);
            obuf[lane * 33 + tl] = sp ? 1.0f : 0.0f;
            partial = ((T1 + T2) + (T3 + T4)) + ((T5 + T6) + T7);
            c0 = nc0; c1 = nc1; x = nx;
        }
        int nrows = TT - tb; if (nrows > 32) nrows = 32;
        for (int k = 0; k + 3 < nrows; k += 4) {
            float4 v = make_float4(obuf[lane * 33 + k],     obuf[lane * 33 + k + 1],
                                   obuf[lane * 33 + k + 2], obuf[lane * 33 + k + 3]);
            *(float4*)(op + tb + k) = v;
        }
        asm volatile("s_waitcnt vmcnt(0)" ::: "memory");
        __syncthreads();
        buf ^= 1;
        x = xbuf[buf][lane];
    }
    #undef STAGE
}

extern "C" void kernel_launch(void* const* d_in, const int* in_sizes, int n_in,
                              void* d_out, int out_size, void* d_ws, size_t ws_size,
                              hipStream_t stream) {
    const float* spikeInput = (const float*)d_in[0];   // [16][2048][1000]
    const float* weight     = (const float*)d_in[1];   // [512][2048]
    float* out = (float*)d_out;                        // [16][512][1000]

    char* ws = (char*)d_ws;
    unsigned long long* bits = (unsigned long long*)ws;            //  4,096,000 B
    signed char*        Bq   = (signed char*)(ws + 4194304);       //  4,194,304 B
    double*             z    = (double*)(ws + 8388608);            // 65,536,000 B
    double*             wpsp = (double*)(ws + 73924608);           // 65,536,000 B

    k_quant<<<(NOUT * NIN) / 256, 256, 0, stream>>>(weight, Bq);
    k_extract<<<dim3(16, 32, 16), 256, 0, stream>>>(spikeInput, bits);
    k_spmm<<<1000, 512, 0, stream>>>(bits, Bq, z);
    k_conv<<<dim3(32, 4, 16), 128, 0, stream>>>(z, wpsp);
    k_scan<<<128, 64, 0, stream>>>(wpsp, out);
}

// Round 10
// 481.653 us; speedup vs baseline: 1.7950x; 1.0081x over previous
//
#include <hip/hip_runtime.h>
#include <hip/hip_bf16.h>
#include <math.h>

#define NB 16
#define NIN 2048
#define NOUT 512
#define TT 1000
#define L_SRM 31

typedef int v4i  __attribute__((ext_vector_type(4)));
typedef int v16i __attribute__((ext_vector_type(16)));

// spread 8 bits -> 8 bytes (0/1) in a u64 (little-endian byte i = bit i)
__device__ __forceinline__ unsigned long long spread8(unsigned int b) {
    unsigned long long x = (unsigned long long)(b & 0xFFu) * 0x0101010101010101ULL;
    x &= 0x8040201008040201ULL;
    x |= x >> 4; x |= x >> 2; x |= x >> 1;
    return x & 0x0101010101010101ULL;
}

// ---------------- kernel 1: quantize W -> 4 signed-i8 planes, o-major --------
__global__ __launch_bounds__(256) void k_quant(const float* __restrict__ W,
                                               signed char* __restrict__ Bq) {
    int idx = blockIdx.x * 256 + threadIdx.x;    // over 512*2048
    int o = idx >> 11, i = idx & (NIN - 1);
    double w = (double)W[o * NIN + i];
    int wq = (int)rint(w * 536870912.0);
    int b0 = (int)(signed char)(wq & 255); int r = (wq - b0) >> 8;
    int b1 = (int)(signed char)(r  & 255); r = (r - b1) >> 8;
    int b2 = (int)(signed char)(r  & 255); r = (r - b2) >> 8;
    int b3 = r;
    size_t e = (size_t)o * NIN + i;
    Bq[e]                = (signed char)b0;
    Bq[e + 1048576]      = (signed char)b1;
    Bq[e + 2097152]      = (signed char)b2;
    Bq[e + 3145728]      = (signed char)b3;
}

// ---------------- kernel 2: ballot-transpose spike extract --------------------
__global__ __launch_bounds__(256) void k_extract(const float* __restrict__ s,
                                                 unsigned long long* __restrict__ bits) {
    __shared__ float tile[64][65];
    int tc = blockIdx.x, ic = blockIdx.y, n = blockIdx.z;
    int t0 = tc * 64, i0 = ic * 64;
    int tid = threadIdx.x;
    int r = tid >> 2, cq = tid & 3;
    const float* rp = s + ((size_t)(n * NIN + i0 + r)) * TT + t0;
    #pragma unroll
    for (int q = 0; q < 4; ++q) {
        int col = cq * 16 + q * 4;
        float4 v = make_float4(0.f, 0.f, 0.f, 0.f);
        if (t0 + col + 3 < TT) v = *(const float4*)(rp + col);
        tile[r][col] = v.x; tile[r][col + 1] = v.y;
        tile[r][col + 2] = v.z; tile[r][col + 3] = v.w;
    }
    __syncthreads();
    int lane = tid & 63, w = tid >> 6;
    #pragma unroll
    for (int k = 0; k < 16; ++k) {
        int tl = w * 16 + k;
        if (t0 + tl >= TT) break;
        unsigned long long m = __ballot(tile[lane][tl] != 0.0f);
        if (lane == 0) bits[((size_t)n * TT + t0 + tl) * 32 + ic] = m;
    }
}

// ---------------- kernel 3: i8-MFMA spike GEMM, 4 exact planes ----------------
__global__ __launch_bounds__(512) void k_spmm(const unsigned long long* __restrict__ bits,
                                              const signed char* __restrict__ Bq,
                                              double* __restrict__ z) {
    __shared__ char Alds[128 * 128];        // 16 KB
    __shared__ char Blds[4][64 * 128];      // 32 KB
    int tid = threadIdx.x;
    int bid = blockIdx.x;                   // 1000
    int o0  = (bid & 7) * 64;
    int nt0 = (bid >> 3) * 128;

    const int arow_w = tid >> 2, q = tid & 3;
    const int p_st = tid >> 7, orow = (tid >> 1) & 63, h = tid & 1;
    const unsigned int* agp = (const unsigned int*)bits + (size_t)(nt0 + arow_w) * 64 + q;
    const signed char*  bgp = Bq + (size_t)p_st * (NOUT * NIN)
                                 + (size_t)(o0 + orow) * NIN + h * 64;
    char* awp = Alds + arow_w * 128;
    const int xra_w = arow_w & 7;
    char* bwp = Blds[p_st] + orow * 128;
    const int xro_w = orow & 7;

    const int l = tid & 63, wv = tid >> 6;
    const int wm = wv >> 1, wn = wv & 1;
    const int arow = wm * 32 + (l & 31), xra = arow & 7;
    const int brow = wn * 32 + (l & 31), xrb = brow & 7;
    const int kg = l >> 5;

    v16i acc0 = {}, acc1 = {}, acc2 = {}, acc3 = {};

    unsigned int aw = agp[0];
    int4 bs0 = ((const int4*)bgp)[0], bs1 = ((const int4*)bgp)[1],
         bs2 = ((const int4*)bgp)[2], bs3 = ((const int4*)bgp)[3];

    for (int ks = 0; ks < 16; ++ks) {
        __syncthreads();
        {
            unsigned long long s0 = spread8(aw), s1 = spread8(aw >> 8),
                               s2 = spread8(aw >> 16), s3 = spread8(aw >> 24);
            ulonglong2 v0; v0.x = s0; v0.y = s1;
            ulonglong2 v1; v1.x = s2; v1.y = s3;
            *(ulonglong2*)(awp + (((2 * q)     ^ xra_w) << 4)) = v0;
            *(ulonglong2*)(awp + (((2 * q + 1) ^ xra_w) << 4)) = v1;
            *(int4*)(bwp + (((h * 4 + 0) ^ xro_w) << 4)) = bs0;
            *(int4*)(bwp + (((h * 4 + 1) ^ xro_w) << 4)) = bs1;
            *(int4*)(bwp + (((h * 4 + 2) ^ xro_w) << 4)) = bs2;
            *(int4*)(bwp + (((h * 4 + 3) ^ xro_w) << 4)) = bs3;
        }
        __syncthreads();
        if (ks < 15) {
            aw = agp[(ks + 1) * 4];
            const int4* g = (const int4*)(bgp + (size_t)(ks + 1) * 128);
            bs0 = g[0]; bs1 = g[1]; bs2 = g[2]; bs3 = g[3];
        }
        #pragma unroll
        for (int ksub = 0; ksub < 4; ++ksub) {
            int ca = ksub * 2 + kg;
            v4i av  = *(const v4i*)(Alds    + arow * 128 + (((ca) ^ xra) << 4));
            v4i bv0 = *(const v4i*)(Blds[0] + brow * 128 + (((ca) ^ xrb) << 4));
            v4i bv1 = *(const v4i*)(Blds[1] + brow * 128 + (((ca) ^ xrb) << 4));
            v4i bv2 = *(const v4i*)(Blds[2] + brow * 128 + (((ca) ^ xrb) << 4));
            v4i bv3 = *(const v4i*)(Blds[3] + brow * 128 + (((ca) ^ xrb) << 4));
            acc0 = __builtin_amdgcn_mfma_i32_32x32x32_i8(av, bv0, acc0, 0, 0, 0);
            acc1 = __builtin_amdgcn_mfma_i32_32x32x32_i8(av, bv1, acc1, 0, 0, 0);
            acc2 = __builtin_amdgcn_mfma_i32_32x32x32_i8(av, bv2, acc2, 0, 0, 0);
            acc3 = __builtin_amdgcn_mfma_i32_32x32x32_i8(av, bv3, acc3, 0, 0, 0);
        }
    }

    #pragma unroll
    for (int r = 0; r < 16; ++r) {
        int row = (r & 3) + 8 * (r >> 2) + 4 * kg;
        long long tot = ((long long)acc3[r] << 24) + ((long long)acc2[r] << 16)
                      + ((long long)acc1[r] << 8)  +  (long long)acc0[r];
        double zv = (double)tot * (1.0 / 536870912.0);
        __builtin_nontemporal_store(zv,
            &z[(size_t)(nt0 + wm * 32 + row) * NOUT + (o0 + wn * 32 + (l & 31))]);
    }
}

// ---------------- kernel 4: temporal conv v2 — async LDS staging --------------
__global__ __launch_bounds__(128) void k_conv(const double* __restrict__ z,
                                              double* __restrict__ wpsp) {
    __shared__ float srm_s[32];
    __shared__ __align__(16) double zs[62 * 128];
    int tid = threadIdx.x;
    if (tid < L_SRM) {
        double t = (double)tid;
        srm_s[tid] = (float)((t / 4.0) * exp(1.0 - t / 4.0));
    }
    int tb = blockIdx.x * 32;
    int oc = blockIdx.y * 128;
    int n  = blockIdx.z;
    const double* zp = z + ((size_t)n * TT) * NOUT + oc;
    int wv = tid >> 6, lane = tid & 63;
    for (int r = wv; r < 62; r += 2) {
        int t = tb - 30 + r;
        if (t >= 0 && t < TT) {
            const double* src = zp + (size_t)t * NOUT + lane * 2;
            __builtin_amdgcn_global_load_lds(
                (const __attribute__((address_space(1))) void*)src,
                (__attribute__((address_space(3))) void*)(&zs[r * 128]),
                16, 0, 0);
        } else {
            double2 zero; zero.x = 0.0; zero.y = 0.0;
            *(double2*)(&zs[r * 128 + lane * 2]) = zero;
        }
    }
    asm volatile("s_waitcnt vmcnt(0)" ::: "memory");
    __syncthreads();
    for (int tl = 0; tl < 32; ++tl) {
        int t = tb + tl;
        if (t >= TT) break;
        double a0 = 0., a1 = 0., a2 = 0., a3 = 0.;
        #pragma unroll
        for (int jj = 0; jj < 28; jj += 4) {
            a0 += (double)srm_s[jj]     * zs[(tl + 30 - jj) * 128 + tid];
            a1 += (double)srm_s[jj + 1] * zs[(tl + 29 - jj) * 128 + tid];
            a2 += (double)srm_s[jj + 2] * zs[(tl + 28 - jj) * 128 + tid];
            a3 += (double)srm_s[jj + 3] * zs[(tl + 27 - jj) * 128 + tid];
        }
        a0 += (double)srm_s[28] * zs[(tl + 2) * 128 + tid];
        a1 += (double)srm_s[29] * zs[(tl + 1) * 128 + tid];
        a2 += (double)srm_s[30] * zs[(tl + 0) * 128 + tid];
        wpsp[((size_t)n * TT + t) * NOUT + oc + tid] = (a0 + a1) + (a2 + a3);
    }
}

// ---------------- kernel 5: spike scan v4 — 2-deep speculative pipeline -------
// At iter t, ALL LDS lookups for step t+2 are issued (7 byte-tables + 4 byte0
// candidates over the 2 unknown spike bits + x). sp_{t-1} folds candidates to
// an (e0,e1) pair off-path; resolve chain = cndmask + add_f64 + cmp (~20cy).
// Table values & add-order identical to v3 => bit-identical results.
__global__ __launch_bounds__(64) void k_scan(const double* __restrict__ wpsp,
                                             float* __restrict__ out) {
    __shared__ float  refTab[64];
    __shared__ double Tb[8][256];                       // 16 KB
    __shared__ __align__(16) double xbuf[2][34 * 64];   // 32 rows + 2 pad rows
    __shared__ float  obuf[64 * 33];
    int lane = threadIdx.x;
    {
        double d = (double)lane;
        refTab[lane] = (lane == 0) ? 0.0f
                     : (float)(-20.0 * (d / 4.0) * exp(1.0 - d / 4.0));
    }
    __syncthreads();
    for (int e = lane; e < 2048; e += 64) {
        int k = e >> 8, m = e & 255;
        double s = 0.0;
        #pragma unroll
        for (int j = 0; j < 8; ++j) {
            int idx = 8 * k + j + 1;
            if (((m >> j) & 1) && idx <= 63) s += (double)refTab[idx];
        }
        Tb[k][m] = s;
    }

    int n  = blockIdx.x >> 3;
    int o0 = (blockIdx.x & 7) << 6;
    const double* wp = wpsp + ((size_t)n * TT) * NOUT + o0;
    float* op = out + ((size_t)(n * NOUT) + o0 + lane) * TT;
    const double* Tb0 = &Tb[0][0];

    int halfSel = lane >> 5;
    int colSel  = (lane & 31) * 2;
    #define STAGE(bf, tb, nrows)                                                   \
        for (int p = 0; p < (nrows) / 2; ++p) {                                    \
            const double* src = wp + (size_t)((tb) + 2 * p + halfSel) * NOUT + colSel; \
            __builtin_amdgcn_global_load_lds(                                      \
                (const __attribute__((address_space(1))) void*)src,                \
                (__attribute__((address_space(3))) void*)(&xbuf[bf][p * 128]),     \
                16, 0, 0);                                                         \
        }

    int buf = 0;
    STAGE(0, 0, 32);
    asm volatile("s_waitcnt vmcnt(0)" ::: "memory");
    __syncthreads();

    // pipeline state (see header comment)
    unsigned long long h = 0ULL;        // committed spike history
    bool sp1 = false;                   // spike at t-1
    double xp = xbuf[0][lane];          // x_0 + partial_0(=0)
    double x1 = xbuf[0][64 + lane];     // x_1
    double partial1 = 0.0;              // partial for step 1
    double p0 = 0., p1 = 0., p2 = 0., p3 = 0., p4 = 0., p5 = 0., p6 = 0.;
    double e0 = 0.0, e1 = 0.0;          // step-0 pair (hist=0)
    double c1_0 = Tb0[0], c1_1 = Tb0[1], c1_2 = Tb0[2], c1_3 = Tb0[3]; // step-1 cands

    for (int tb = 0; tb < TT; tb += 32) {
        int nnext = TT - (tb + 32); if (nnext > 32) nnext = 32;
        if (nnext > 0) { STAGE(buf ^ 1, tb + 32, nnext); }
        #pragma unroll
        for (int tl = 0; tl < 32; ++tl) {
            // commit sp_{t-1}
            h = (h << 1) | (unsigned long long)sp1;
            unsigned long long hs = h << 2;     // step t+2 view; bits 0,1 = 0
            // speculative loads for step t+2 (results used at iter t+2)
            double q1 = Tb[1][(unsigned)((hs >>  8) & 255)];
            double q2 = Tb[2][(unsigned)((hs >> 16) & 255)];
            double q3 = Tb[3][(unsigned)((hs >> 24) & 255)];
            double q4 = Tb[4][(unsigned)((hs >> 32) & 255)];
            double q5 = Tb[5][(unsigned)((hs >> 40) & 255)];
            double q6 = Tb[6][(unsigned)((hs >> 48) & 255)];
            double q7 = Tb[7][(unsigned)((hs >> 56) & 255)];
            unsigned m = (unsigned)(hs & 255);  // bits 0,1 clear -> 32B aligned
            double2 nc01 = *(const double2*)(Tb0 + m);
            double2 nc23 = *(const double2*)(Tb0 + m + 2);
            double nx = xbuf[buf][(tl + 2) * 64 + lane];
            // fold sp_{t-1} into step-(t+1) candidate pair (off critical path)
            double e0n = sp1 ? c1_2 : c1_0;
            double e1n = sp1 ? c1_3 : c1_1;
            // sum iter-(t-1) loads -> partial for step t+1
            double np1 = ((p0 + p1) + (p2 + p3)) + ((p4 + p5) + p6);
            // resolve step t  (critical chain: cndmask + add + cmp)
            double u = xp + (sp1 ? e1 : e0);
            bool spt = (u >= 10.0);
            obuf[lane * 33 + tl] = spt ? 1.0f : 0.0f;
            // xp for step t+1
            double nxp = x1 + np1;
            // rotate
            sp1 = spt;
            e0 = e0n; e1 = e1n;
            partial1 = np1;
            xp = nxp; x1 = nx;
            p0 = q1; p1 = q2; p2 = q3; p3 = q4; p4 = q5; p5 = q6; p6 = q7;
            c1_0 = nc01.x; c1_1 = nc01.y; c1_2 = nc23.x; c1_3 = nc23.y;
        }
        int nrows = TT - tb; if (nrows > 32) nrows = 32;
        for (int k = 0; k + 3 < nrows; k += 4) {
            float4 v = make_float4(obuf[lane * 33 + k],     obuf[lane * 33 + k + 1],
                                   obuf[lane * 33 + k + 2], obuf[lane * 33 + k + 3]);
            *(float4*)(op + tb + k) = v;
        }
        asm volatile("s_waitcnt vmcnt(0)" ::: "memory");
        __syncthreads();
        buf ^= 1;
        // repair 2-step x lookahead across the chunk boundary
        xp = xbuf[buf][lane] + partial1;
        x1 = xbuf[buf][64 + lane];
    }
    #undef STAGE
}

extern "C" void kernel_launch(void* const* d_in, const int* in_sizes, int n_in,
                              void* d_out, int out_size, void* d_ws, size_t ws_size,
                              hipStream_t stream) {
    const float* spikeInput = (const float*)d_in[0];   // [16][2048][1000]
    const float* weight     = (const float*)d_in[1];   // [512][2048]
    float* out = (float*)d_out;                        // [16][512][1000]

    char* ws = (char*)d_ws;
    unsigned long long* bits = (unsigned long long*)ws;            //  4,096,000 B
    signed char*        Bq   = (signed char*)(ws + 4194304);       //  4,194,304 B
    double*             z    = (double*)(ws + 8388608);            // 65,536,000 B
    double*             wpsp = (double*)(ws + 73924608);           // 65,536,000 B

    k_quant<<<(NOUT * NIN) / 256, 256, 0, stream>>>(weight, Bq);
    k_extract<<<dim3(16, 32, 16), 256, 0, stream>>>(spikeInput, bits);
    k_spmm<<<1000, 512, 0, stream>>>(bits, Bq, z);
    k_conv<<<dim3(32, 4, 16), 128, 0, stream>>>(z, wpsp);
    k_scan<<<128, 64, 0, stream>>>(wpsp, out);
}